// Round 1
// baseline (157.967 us; speedup 1.0000x reference)
//
#include <hip/hip_runtime.h>
#include <math.h>

#define TPB 256

// Per-pair precompute: spherical harmonics (L_MAX=3, 16 cols) + 34-channel
// cubic-hermite radial spline with cutoff. One thread = one pair for the
// compute phase; results staged in LDS; block-coalesced writes.
__global__ __launch_bounds__(TPB) void precompute_kernel(
    const float* __restrict__ pos,    // (N_ATOMS,3)
    const float* __restrict__ cells,  // (N_STRUCT,3,3) row-major
    const int*   __restrict__ shifts, // (N,3)
    const int*   __restrict__ cidx,   // (N,)
    const int*   __restrict__ nidx,   // (N,)
    const int*   __restrict__ spair,  // (N,)
    const int*   __restrict__ cspec,  // (N,)
    const int*   __restrict__ nspec,  // (N,)
    const float* __restrict__ ls,     // (9,)
    const float* __restrict__ sv,     // (1001,34)
    const float* __restrict__ sd,     // (1001,34)
    float* __restrict__ outY,         // (N,16)
    float* __restrict__ outR,         // (N,34)
    int n)
{
    __shared__ float sY[TPB][17];   // +1 pad: stride 17 (odd) -> conflict-free
    __shared__ float sW[TPB][5];    // w0..w3, row-offset (as int); stride 5 odd

    const int tid  = threadIdx.x;
    const int base = blockIdx.x * TPB;
    const int p    = base + tid;

    if (p < n) {
        const int ci = cidx[p], ni = nidx[p], sp = spair[p];
        const int cs = cspec[p], ns = nspec[p];
        const int s0 = shifts[3*p], s1 = shifts[3*p+1], s2 = shifts[3*p+2];
        const float f0 = (float)s0, f1 = (float)s1, f2 = (float)s2;
        const float* cl = cells + sp * 9;

        float vx = pos[3*ni+0] - pos[3*ci+0] + f0*cl[0] + f1*cl[3] + f2*cl[6];
        float vy = pos[3*ni+1] - pos[3*ci+1] + f0*cl[1] + f1*cl[4] + f2*cl[7];
        float vz = pos[3*ni+2] - pos[3*ci+2] + f0*cl[2] + f1*cl[5] + f2*cl[8];

        float rsq = vx*vx + vy*vy + vz*vz;
        float r   = sqrtf(rsq);
        float inv = 1.0f / r;
        float x = vx*inv, y = vy*inv, z = vz*inv;
        float x2 = x*x, y2 = y*y, z2 = z*z;

        // Real spherical harmonics * sqrt(4*pi), reference column order.
        sY[tid][0]  = 1.0f;
        sY[tid][1]  = 1.7320508075688772f * y;
        sY[tid][2]  = 1.7320508075688772f * z;
        sY[tid][3]  = 1.7320508075688772f * x;
        sY[tid][4]  = 3.872983346207417f  * x * y;
        sY[tid][5]  = 3.872983346207417f  * y * z;
        sY[tid][6]  = 1.118033988749895f  * (3.0f*z2 - 1.0f);
        sY[tid][7]  = 3.872983346207417f  * x * z;
        sY[tid][8]  = 1.9364916731037085f * (x2 - y2);
        sY[tid][9]  = 2.091650066335189f  * y * (3.0f*x2 - y2);
        sY[tid][10] = 10.246950765959598f * x * y * z;
        sY[tid][11] = 1.6201851746019651f * y * (5.0f*z2 - 1.0f);
        sY[tid][12] = 1.3228756555322954f * z * (5.0f*z2 - 3.0f);
        sY[tid][13] = 1.6201851746019651f * x * (5.0f*z2 - 1.0f);
        sY[tid][14] = 5.123475382979799f  * z * (x2 - y2);
        sY[tid][15] = 2.091650066335189f  * x * (x2 - 3.0f*y2);

        // Radial spline metadata.
        const float denom = 0.1f + expf(ls[cs]) + expf(ls[ns]);
        const float xx = r / denom;
        const bool  valid = xx < 10.0f;
        const float cx = valid ? xx : 5.0f;
        const float DELTA = 0.01f;
        int idx = (int)floorf(cx / DELTA);
        idx = idx < 0 ? 0 : (idx > 999 ? 999 : idx);
        const float t  = (cx - (float)idx * DELTA) / DELTA;
        const float t2 = t*t, t3 = t2*t;
        const float h00 =  2.0f*t3 - 3.0f*t2 + 1.0f;
        const float h10 =        t3 - 2.0f*t2 + t;
        const float h01 = -2.0f*t3 + 3.0f*t2;
        const float h11 =        t3 -      t2;
        // Cutoff exactly as reference (NOT clamped beyond r_cut).
        const float cut = (r < 4.5f) ? 1.0f
                        : (1.0f + cosf((r - 4.5f) * 6.2831853071795864f));
        const float g = valid ? cut : 0.0f;
        sW[tid][0] = h00 * g;
        sW[tid][1] = h10 * g * DELTA;
        sW[tid][2] = h01 * g;
        sW[tid][3] = h11 * g * DELTA;
        sW[tid][4] = __int_as_float(idx * 34);   // row byte-offset base (elems)
    }
    __syncthreads();

    const int remain = n - base;
    const int nact   = remain >= TPB ? TPB : remain;

    // Coalesced Y writes: 256x16 tile.
    {
        float* Yb = outY + (size_t)base * 16;
        const int nY = nact * 16;
        #pragma unroll
        for (int j = 0; j < 16; ++j) {
            int e = j * TPB + tid;
            if (e < nY) {
                int pp = e >> 4, cc = e & 15;
                Yb[e] = sY[pp][cc];
            }
        }
    }
    // Coalesced radial writes: 256x34 tile; per-element spline gather (L2-hot).
    {
        float* Rb = outR + (size_t)base * 34;
        const int nR = nact * 34;
        #pragma unroll
        for (int k = 0; k < 34; ++k) {
            int e = k * TPB + tid;
            if (e < nR) {
                int pp = e / 34;
                int cc = e - pp * 34;
                float w0 = sW[pp][0], w1 = sW[pp][1];
                float w2 = sW[pp][2], w3 = sW[pp][3];
                int rb = __float_as_int(sW[pp][4]);
                float v = w0 * sv[rb + cc]      + w1 * sd[rb + cc]
                        + w2 * sv[rb + 34 + cc] + w3 * sd[rb + 34 + cc];
                Rb[e] = v;
            }
        }
    }
}

extern "C" void kernel_launch(void* const* d_in, const int* in_sizes, int n_in,
                              void* d_out, int out_size, void* d_ws, size_t ws_size,
                              hipStream_t stream) {
    const float* pos    = (const float*)d_in[0];
    const float* cells  = (const float*)d_in[1];
    const int*   shifts = (const int*)d_in[2];
    const int*   cidx   = (const int*)d_in[3];
    const int*   nidx   = (const int*)d_in[4];
    const int*   spair  = (const int*)d_in[5];
    const int*   cspec  = (const int*)d_in[6];
    const int*   nspec  = (const int*)d_in[7];
    const float* ls     = (const float*)d_in[8];
    const float* sv     = (const float*)d_in[9];
    const float* sd     = (const float*)d_in[10];

    const int n = in_sizes[3];              // N_PAIRS
    float* outY = (float*)d_out;            // (N,16)
    float* outR = outY + (size_t)n * 16;    // (N,34)

    const int grid = (n + TPB - 1) / TPB;
    hipLaunchKernelGGL(precompute_kernel, dim3(grid), dim3(TPB), 0, stream,
                       pos, cells, shifts, cidx, nidx, spair, cspec, nspec,
                       ls, sv, sd, outY, outR, n);
}